// Round 10
// baseline (188.333 us; speedup 1.0000x reference)
//
#include <hip/hip_runtime.h>

#define B_SZ 1024
#define DIN 512
#define HH 512   // H
#define DOUT 512

typedef short bf16x8 __attribute__((ext_vector_type(8)));
typedef float f32x4 __attribute__((ext_vector_type(4)));

__device__ __forceinline__ unsigned short f2bf(float f) {
    unsigned int u = __float_as_uint(f);
    u += 0x7FFFu + ((u >> 16) & 1u);          // RTNE
    return (unsigned short)(u >> 16);
}
__device__ __forceinline__ float bf2f(unsigned short s) {
    return __uint_as_float(((unsigned int)s) << 16);
}

// pack 8 fp32 -> 8 bf16 (term==1 -> lo residual, else hi)
__device__ __forceinline__ uint4 cvt8(const float4& a0, const float4& a1, int term) {
    const float av[8] = {a0.x, a0.y, a0.z, a0.w, a1.x, a1.y, a1.z, a1.w};
    unsigned int p[4];
    #pragma unroll
    for (int q = 0; q < 4; ++q) {
        float f0 = av[2 * q], f1 = av[2 * q + 1];
        unsigned short h0 = f2bf(f0), h1 = f2bf(f1);
        if (term == 1) { h0 = f2bf(f0 - bf2f(h0)); h1 = f2bf(f1 - bf2f(h1)); }
        p[q] = (unsigned int)h0 | ((unsigned int)h1 << 16);
    }
    uint4 v; v.x = p[0]; v.y = p[1]; v.z = p[2]; v.w = p[3];
    return v;
}

// async global->LDS, 16B/lane. LDS dest = WAVE-UNIFORM base + lane*16 (m104);
// global src is per-lane (m173). Proven correct in r7/r8/r9 runs.
__device__ __forceinline__ void gload_lds16(const void* g, void* l) {
    __builtin_amdgcn_global_load_lds(
        (__attribute__((address_space(1))) void*)g,
        (__attribute__((address_space(3))) void*)l, 16, 0, 0);
}

// counted vmem wait (T4): wait until <= N vmem ops outstanding.
template <int N>
__device__ __forceinline__ void waitcnt_vm() {
    asm volatile("s_waitcnt vmcnt(%0)" :: "n"(N) : "memory");
}

// ---------------------------------------------------------------------------
// bf16 hi/lo split GEMM scheme (K'=1536 = 3 terms x 512):
//   C = AhiWhi + AloWhi + AhiWlo  (~fp32 accurate)
// ---------------------------------------------------------------------------
__device__ __forceinline__ void convW_body(const float* __restrict__ W,
                                           uint4* __restrict__ dst, int t) {
    const int lane = t & 63;
    const int fb   = t >> 6;         // ks*32 + nf
    const int ks   = fb >> 5;
    const int nf   = fb & 31;
    const int col  = nf * 16 + (lane & 15);
    const int kb   = ks * 32 + ((lane >> 4) << 3);
    const int term = kb >> 9;        // 0,1,2 -> hi,hi,lo
    const int c0   = kb & 511;
    unsigned short o[8];
    #pragma unroll
    for (int j = 0; j < 8; ++j) {
        const float f = W[(size_t)(c0 + j) * 512 + col];
        unsigned short hi = f2bf(f);
        o[j] = (term == 2) ? f2bf(f - bf2f(hi)) : hi;
    }
    uint4 v;
    v.x = (unsigned int)o[0] | ((unsigned int)o[1] << 16);
    v.y = (unsigned int)o[2] | ((unsigned int)o[3] << 16);
    v.z = (unsigned int)o[4] | ((unsigned int)o[5] << 16);
    v.w = (unsigned int)o[6] | ((unsigned int)o[7] << 16);
    dst[t] = v;
}

// scan weight packs, consumption-ordered (unchanged):
//  wdg[i*64+l] = diag elem (row i, col 64*(i>>6)+l), masked (col>i), row-511 pad
//  wbk[CB + ((s*NK+k)*64+l)] = bulk elem (row 64C+s, col 64*(C+1+k)+l), no mask
template <int C>
__device__ __forceinline__ void pack_bulk(const float* __restrict__ W_hh,
                                          const float* __restrict__ b_hh,
                                          float2* __restrict__ wbk, int e) {
    constexpr int NK = 7 - C;
    constexpr int CB = (C==0?0:C==1?7:C==2?13:C==3?18:C==4?22:C==5?25:27) * 4096;
    const int s   = e / (NK * 64);           // compile-time NK -> magic mul
    const int rem = e - s * (NK * 64);
    const int row = 64 * C + s;
    const int col = 64 * (C + 1) + rem;
    float2 o;
    o.x = W_hh[(size_t)row * 512 + col];
    o.y = b_hh[(size_t)row * 512 + col];
    wbk[CB + e] = o;
}

// ---------------------------------------------------------------------------
// prep_all (block-range dispatch), 1344 blocks — unchanged (passing r5/r8/r9).
// ---------------------------------------------------------------------------
__global__ __launch_bounds__(256)
void prep_all(const float* __restrict__ W_hh, const float* __restrict__ b_hh,
              float2* __restrict__ wdg, float2* __restrict__ wbk,
              const float* __restrict__ W_in, uint4* __restrict__ Bin,
              const float* __restrict__ W_out, uint4* __restrict__ Bout) {
    const int b = blockIdx.x;
    const int tid = threadIdx.x;
    if (b < 128) {
        const int idx = b * 256 + tid;       // over 512*64
        const int i = idx >> 6, l = idx & 63;
        float2 o;
        if (i < 511 && l > (i & 63)) {
            const int col = ((i >> 6) << 6) + l;
            o.x = W_hh[(size_t)i * 512 + col];
            o.y = b_hh[(size_t)i * 512 + col];
        } else { o.x = 0.0f; o.y = -1.0f; }
        wdg[idx] = o;
    } else if (b < 576) {
        const int rb = b - 128;
        if      (rb < 112) pack_bulk<0>(W_hh, b_hh, wbk, (rb      ) * 256 + tid);
        else if (rb < 208) pack_bulk<1>(W_hh, b_hh, wbk, (rb - 112) * 256 + tid);
        else if (rb < 288) pack_bulk<2>(W_hh, b_hh, wbk, (rb - 208) * 256 + tid);
        else if (rb < 352) pack_bulk<3>(W_hh, b_hh, wbk, (rb - 288) * 256 + tid);
        else if (rb < 400) pack_bulk<4>(W_hh, b_hh, wbk, (rb - 352) * 256 + tid);
        else if (rb < 432) pack_bulk<5>(W_hh, b_hh, wbk, (rb - 400) * 256 + tid);
        else               pack_bulk<6>(W_hh, b_hh, wbk, (rb - 432) * 256 + tid);
    } else if (b < 960) {
        convW_body(W_in, Bin, (b - 576) * 256 + tid);
    } else {
        convW_body(W_out, Bout, (b - 960) * 256 + tid);
    }
}

// ---------------------------------------------------------------------------
// MFMA GEMM: 512 threads (8 waves = 2/SIMD). Unchanged (passing r5/r8/r9).
// ---------------------------------------------------------------------------
template <bool ACT>
__global__ __launch_bounds__(512, 2)
void mfma_gemm(const float* __restrict__ A,    // [1024][512] fp32
               const uint4* __restrict__ Bg,   // [48][32][64] uint4
               const float* __restrict__ bias,
               float* __restrict__ C) {
    __shared__ uint4 lds[2][768];
    const int tid  = threadIdx.x;
    const int lane = tid & 63;
    const int w    = tid >> 6;
    const int mfw  = w & 3;
    const int nfw  = w >> 2;
    const int mf0  = blockIdx.x * 4;
    const int nf0  = blockIdx.y * 2;

    const int ks_s = tid >> 8;
    const int mf_s = (tid >> 6) & 3;
    const int arow = (mf0 + mf_s) * 16 + (lane & 15);
    const int koff = (lane >> 4) << 3;
    const int bks  = tid >> 7;
    const int bnf  = (tid >> 6) & 1;

    float4 Ra0, Ra1; uint4 R2;
    auto stage = [&](int s) {
        const int kp = (s * 2 + ks_s) * 32 + koff;
        const int c  = kp & 511;
        Ra0 = *(const float4*)&A[(size_t)arow * 512 + c];
        Ra1 = *(const float4*)&A[(size_t)arow * 512 + c + 4];
        if (tid < 256)
            R2 = Bg[(size_t)((s * 2 + bks) * 32 + nf0 + bnf) * 64 + lane];
    };
    auto write_tile = [&](int buf, int s) {
        const int kp = (s * 2 + ks_s) * 32 + koff;
        lds[buf][ks_s * 256 + mf_s * 64 + lane] = cvt8(Ra0, Ra1, kp >> 9);
        if (tid < 256)
            lds[buf][512 + bks * 128 + bnf * 64 + lane] = R2;
    };

    f32x4 acc = {0.f, 0.f, 0.f, 0.f};

    stage(0);
    write_tile(0, 0);
    stage(1);
    __syncthreads();

    for (int s = 0; s < 24; ++s) {
        const int cur = s & 1;
        if (s + 1 < 24) write_tile(cur ^ 1, s + 1);
        if (s + 2 < 24) stage(s + 2);
        __builtin_amdgcn_sched_barrier(0);

        bf16x8 aF0 = *(const bf16x8*)&lds[cur][          mfw * 64 + lane];
        bf16x8 aF1 = *(const bf16x8*)&lds[cur][256     + mfw * 64 + lane];
        bf16x8 bF0 = *(const bf16x8*)&lds[cur][512     + nfw * 64 + lane];
        bf16x8 bF1 = *(const bf16x8*)&lds[cur][512+128 + nfw * 64 + lane];
        acc = __builtin_amdgcn_mfma_f32_16x16x32_bf16(aF0, bF0, acc, 0, 0, 0);
        acc = __builtin_amdgcn_mfma_f32_16x16x32_bf16(aF1, bF1, acc, 0, 0, 0);
        __syncthreads();
    }

    const int colg  = (nf0 + nfw) * 16 + (lane & 15);
    const float bv  = bias[colg];
    const int rbase = (mf0 + mfw) * 16 + ((lane >> 4) << 2);
    #pragma unroll
    for (int r = 0; r < 4; ++r) {
        float v = acc[r] + bv;
        if (ACT) { v = fmaxf(v, 0.f); v = v * v; }
        C[(size_t)(rbase + r) * 512 + colg] = v;
    }
}

// ---------------------------------------------------------------------------
// Sequential triangular scan, v10: PARITY WAVE-SPLIT for 2 waves/SIMD.
// v8==v9 (60.6us) proved the scan is intra-wave-latency-bound at 1 wave/SIMD
// (1024 rows = 1024 waves = 4/CU). Only more waves fixes that: 256 blocks x
// 8 waves (512 thr). Wave pair (r, r+4) owns row bid*4+r: half 0 owns EVEN
// k-groups {0,2,4,6}, half 1 ODD {1,3,5,7} -> 2048 waves = 2/SIMD. Each
// hr[k] accumulator lives permanently in one wave; chunk-C diag (group C,
// parity C&1) runs in its owner wave, then hr[C] final is handed to the
// partner via a 1KB LDS comm buffer + __syncthreads. Bulk: both halves
// stream their own groups from the shared tiles; staging/vmcnt/s_barrier
// pipeline identical to v9 (staging by tid<256; non-staging waves' counted
// waits pass trivially, the s_barrier gates them).
// Per-column FP accumulation order IDENTICAL to v2-v9 (same chunk order,
// same s order, same owner) -> bitwise-same result.
// ---------------------------------------------------------------------------
template <int C, int H>
__device__ __forceinline__ void bulk_half(const float2* __restrict__ tile,
                                          const float his[8], float hrl[4],
                                          int lane) {
    constexpr int NK = 7 - C;
    constexpr int I0 = (C + 2 - H) >> 1;     // first local idx with 2i+H >= C+1
    #pragma unroll
    for (int s = 0; s < 8; ++s) {
        #pragma unroll
        for (int i = I0; i < 4; ++i) {
            const float2 wv = tile[(s * NK + (2 * i + H - C - 1)) * 64 + lane];
            const float tv = fmaf(his[s], wv.x, wv.y);
            const float rv = fmaxf(tv, 0.f);
            hrl[i] = fmaf(rv, rv, hrl[i]);
        }
    }
}

template <int C>
__device__ __forceinline__ void scan_chunk(const float2* __restrict__ wdg,
                                           const float2* __restrict__ wbk,
                                           float2 (* __restrict__ smb)[3584],
                                           float (* __restrict__ comm)[64],
                                           float hrl[4], int lane, int half,
                                           int r, int tid) {
    constexpr int NK = 7 - C;
    constexpr int CB = (C==0?0:C==1?7:C==2?13:C==3?18:C==4?22:C==5?25:C==6?27:27) * 4096;
    constexpr int IO = C >> 1;               // local idx of group C in owner
    const bool owner = (half == (C & 1));    // wave-uniform

    const char* gch = (const char*)(wbk + CB);
    char* lbase = (char*)(&smb[0][0]) + ((tid >> 6) << 10);   // + wave*1024
    auto stage = [&](int t, int buf) {
        const char* g = gch + (size_t)t * (NK * 4096);
        char* l = lbase + buf * 28672;
        #pragma unroll
        for (int u = 0; u < NK; ++u)         // dest wave-uniform; HW adds lane*16
            gload_lds16(g + (size_t)((u << 8) + tid) * 16, l + (u << 12));
    };
    // tiles 0,1 issued at chunk entry by staging waves (flight hides under diag;
    // buffers 0,1 were last read 2+ barriers ago in prev chunk -> safe)
    if constexpr (NK > 0) {
        if (tid < 256) { stage(0, 0); stage(1, 1); }
    }
    __builtin_amdgcn_sched_barrier(0);

    // serial diagonal in the OWNER waves only (rotating register window, v9)
    if (owner) {
        const float2* dptr = wdg + (64 * C) * 64 + lane;
        float2 Wd[16];
        #pragma unroll
        for (int q = 0; q < 16; ++q) Wd[q] = dptr[q * 64];
        for (int t = 0; t < 4; ++t) {
            #pragma unroll
            for (int q = 0; q < 16; ++q) {
                const int s = t * 16 + q;
                if (!(C == 7 && s == 63)) {  // no global step 511
                    const float hi = __uint_as_float(
                        __builtin_amdgcn_readlane(__float_as_uint(hrl[IO]), s));
                    const float tv = fmaf(hi, Wd[q].x, Wd[q].y);
                    const float rv = fmaxf(tv, 0.f);
                    hrl[IO] = fmaf(rv, rv, hrl[IO]);
                }
                if (t < 3) Wd[q] = dptr[(s + 16) * 64];
            }
        }
    }

    if constexpr (NK > 0) {
        // handoff: partner needs final hr[C] for its readlanes
        if (owner) comm[r][lane] = hrl[IO];
        __syncthreads();                     // also drains staging vmcnt: tiles 0,1 in
        const float hsrc = owner ? hrl[IO] : comm[r][lane];

        #pragma unroll
        for (int t = 0; t < 8; ++t) {
            if (tid < 256 && t + 2 < 8) stage(t + 2, (t + 2) & 3);
            __builtin_amdgcn_sched_barrier(0);     // stage stays above wait
            if      (t <= 5) waitcnt_vm<2 * NK>(); // tile t done; t+1,t+2 fly
            else if (t == 6) waitcnt_vm<NK>();
            else             waitcnt_vm<0>();      // clean FIFO for next chunk
            __builtin_amdgcn_s_barrier();          // all waves: tile t ready
            __builtin_amdgcn_sched_barrier(0);     // reads stay below barrier

            float his[8];                          // hoisted off critical path
            #pragma unroll
            for (int s = 0; s < 8; ++s)
                his[s] = __uint_as_float(__builtin_amdgcn_readlane(
                    __float_as_uint(hsrc), t * 8 + s));
            if (half == 0) bulk_half<C, 0>(&smb[t & 3][0], his, hrl, lane);
            else           bulk_half<C, 1>(&smb[t & 3][0], his, hrl, lane);
        }
    }
}

__global__ __launch_bounds__(512, 2)
void scan_kernel(const float2* __restrict__ wdg, const float2* __restrict__ wbk,
                 float* __restrict__ h) {
    __shared__ __align__(16) float2 smb[4][3584];   // 4 x 28KB tile buffers
    __shared__ float comm[4][64];                   // hr[C] handoff, 1KB
    const int tid  = threadIdx.x;
    const int lane = tid & 63;
    const int w    = tid >> 6;
    const int r    = w & 3;                  // row slot in block
    const int half = w >> 2;                 // 0: even k-groups, 1: odd
    float* hrow = h + (size_t)(blockIdx.x * 4 + r) * HH;

    float hrl[4];                            // group g = 2*i + half
    #pragma unroll
    for (int i = 0; i < 4; ++i) hrl[i] = hrow[lane + 64 * (2 * i + half)];

    scan_chunk<0>(wdg, wbk, smb, comm, hrl, lane, half, r, tid);
    scan_chunk<1>(wdg, wbk, smb, comm, hrl, lane, half, r, tid);
    scan_chunk<2>(wdg, wbk, smb, comm, hrl, lane, half, r, tid);
    scan_chunk<3>(wdg, wbk, smb, comm, hrl, lane, half, r, tid);
    scan_chunk<4>(wdg, wbk, smb, comm, hrl, lane, half, r, tid);
    scan_chunk<5>(wdg, wbk, smb, comm, hrl, lane, half, r, tid);
    scan_chunk<6>(wdg, wbk, smb, comm, hrl, lane, half, r, tid);
    scan_chunk<7>(wdg, wbk, smb, comm, hrl, lane, half, r, tid);

    #pragma unroll
    for (int i = 0; i < 4; ++i) hrow[lane + 64 * (2 * i + half)] = hrl[i];
}

// ---------------------------------------------------------------------------
// workspace layout (6.2 MB):
//   [0x000000, 0x040000) wdg  (512*64 f2 = 256 KB)
//   [0x040000, 0x120000) wbk  (114688 f2 = 896 KB)
//   [0x120000, 0x320000) h    (1024*512 fp32 = 2 MB)
//   [0x320000, 0x4A0000) Bin  (48*32*64 uint4 = 1.5 MB)
//   [0x4A0000, 0x620000) Bout (1.5 MB)
// ---------------------------------------------------------------------------
extern "C" void kernel_launch(void* const* d_in, const int* in_sizes, int n_in,
                              void* d_out, int out_size, void* d_ws, size_t ws_size,
                              hipStream_t stream) {
    const float* x     = (const float*)d_in[0];
    const float* W_in  = (const float*)d_in[1];
    const float* b_in  = (const float*)d_in[2];
    const float* W_hh  = (const float*)d_in[3];
    const float* b_hh  = (const float*)d_in[4];
    const float* W_out = (const float*)d_in[5];
    const float* b_out = (const float*)d_in[6];
    float* out = (float*)d_out;

    char* ws = (char*)d_ws;
    float2* wdg  = (float2*)ws;
    float2* wbk  = (float2*)(ws + 0x040000u);
    float*  h    = (float*)(ws + 0x120000u);
    uint4*  Bin  = (uint4*)(ws + 0x320000u);
    uint4*  Bout = (uint4*)(ws + 0x4A0000u);

    // 1) prep: scan-weight packs + W_in/W_out bf16 hi/lo frag-linear split
    prep_all<<<dim3(1344), dim3(256), 0, stream>>>(W_hh, b_hh, wdg, wbk,
                                                   W_in, Bin, W_out, Bout);

    // 2) h0 = relu^2(x @ W_in + b_in)  (A-side split fused into staging)
    mfma_gemm<true><<<dim3(16, 16), dim3(512), 0, stream>>>(x, Bin, b_in, h);

    // 3) sequential triangular scan, in-place on h (parity wave-split)
    scan_kernel<<<dim3(256), dim3(512), 0, stream>>>(wdg, wbk, h);

    // 4) out = h @ W_out + b_out  (A-side split fused into staging)
    mfma_gemm<false><<<dim3(16, 16), dim3(512), 0, stream>>>(h, Bout, b_out, out);
}

// Round 11
// 151.143 us; speedup vs baseline: 1.2461x; 1.2461x over previous
//
#include <hip/hip_runtime.h>

#define B_SZ 1024
#define DIN 512
#define HH 512   // H
#define DOUT 512

typedef short bf16x8 __attribute__((ext_vector_type(8)));
typedef float f32x4 __attribute__((ext_vector_type(4)));

__device__ __forceinline__ unsigned short f2bf(float f) {
    unsigned int u = __float_as_uint(f);
    u += 0x7FFFu + ((u >> 16) & 1u);          // RTNE
    return (unsigned short)(u >> 16);
}
__device__ __forceinline__ float bf2f(unsigned short s) {
    return __uint_as_float(((unsigned int)s) << 16);
}

// pack 8 fp32 -> 8 bf16 (term==1 -> lo residual, else hi)
__device__ __forceinline__ uint4 cvt8(const float4& a0, const float4& a1, int term) {
    const float av[8] = {a0.x, a0.y, a0.z, a0.w, a1.x, a1.y, a1.z, a1.w};
    unsigned int p[4];
    #pragma unroll
    for (int q = 0; q < 4; ++q) {
        float f0 = av[2 * q], f1 = av[2 * q + 1];
        unsigned short h0 = f2bf(f0), h1 = f2bf(f1);
        if (term == 1) { h0 = f2bf(f0 - bf2f(h0)); h1 = f2bf(f1 - bf2f(h1)); }
        p[q] = (unsigned int)h0 | ((unsigned int)h1 << 16);
    }
    uint4 v; v.x = p[0]; v.y = p[1]; v.z = p[2]; v.w = p[3];
    return v;
}

// async global->LDS, 16B/lane. LDS dest = WAVE-UNIFORM base + lane*16 (m104);
// global src is per-lane (m173). Proven correct in r7/r8/r9 runs.
__device__ __forceinline__ void gload_lds16(const void* g, void* l) {
    __builtin_amdgcn_global_load_lds(
        (__attribute__((address_space(1))) void*)g,
        (__attribute__((address_space(3))) void*)l, 16, 0, 0);
}

// ---------------------------------------------------------------------------
// bf16 hi/lo split GEMM scheme (K'=1536 = 3 terms x 512):
//   C = AhiWhi + AloWhi + AhiWlo  (~fp32 accurate)
// ---------------------------------------------------------------------------
__device__ __forceinline__ void convW_body(const float* __restrict__ W,
                                           uint4* __restrict__ dst, int t) {
    const int lane = t & 63;
    const int fb   = t >> 6;         // ks*32 + nf
    const int ks   = fb >> 5;
    const int nf   = fb & 31;
    const int col  = nf * 16 + (lane & 15);
    const int kb   = ks * 32 + ((lane >> 4) << 3);
    const int term = kb >> 9;        // 0,1,2 -> hi,hi,lo
    const int c0   = kb & 511;
    unsigned short o[8];
    #pragma unroll
    for (int j = 0; j < 8; ++j) {
        const float f = W[(size_t)(c0 + j) * 512 + col];
        unsigned short hi = f2bf(f);
        o[j] = (term == 2) ? f2bf(f - bf2f(hi)) : hi;
    }
    uint4 v;
    v.x = (unsigned int)o[0] | ((unsigned int)o[1] << 16);
    v.y = (unsigned int)o[2] | ((unsigned int)o[3] << 16);
    v.z = (unsigned int)o[4] | ((unsigned int)o[5] << 16);
    v.w = (unsigned int)o[6] | ((unsigned int)o[7] << 16);
    dst[t] = v;
}

// scan weight packs, consumption-ordered (unchanged):
//  wdg[i*64+l] = diag elem (row i, col 64*(i>>6)+l), masked (col>i), row-511 pad
//  wbk[CB + ((s*NK+k)*64+l)] = bulk elem (row 64C+s, col 64*(C+1+k)+l), no mask
template <int C>
__device__ __forceinline__ void pack_bulk(const float* __restrict__ W_hh,
                                          const float* __restrict__ b_hh,
                                          float2* __restrict__ wbk, int e) {
    constexpr int NK = 7 - C;
    constexpr int CB = (C==0?0:C==1?7:C==2?13:C==3?18:C==4?22:C==5?25:27) * 4096;
    const int s   = e / (NK * 64);           // compile-time NK -> magic mul
    const int rem = e - s * (NK * 64);
    const int row = 64 * C + s;
    const int col = 64 * (C + 1) + rem;
    float2 o;
    o.x = W_hh[(size_t)row * 512 + col];
    o.y = b_hh[(size_t)row * 512 + col];
    wbk[CB + e] = o;
}

// ---------------------------------------------------------------------------
// prep_all (block-range dispatch), 1344 blocks — unchanged (passing r5-r9).
// ---------------------------------------------------------------------------
__global__ __launch_bounds__(256)
void prep_all(const float* __restrict__ W_hh, const float* __restrict__ b_hh,
              float2* __restrict__ wdg, float2* __restrict__ wbk,
              const float* __restrict__ W_in, uint4* __restrict__ Bin,
              const float* __restrict__ W_out, uint4* __restrict__ Bout) {
    const int b = blockIdx.x;
    const int tid = threadIdx.x;
    if (b < 128) {
        const int idx = b * 256 + tid;       // over 512*64
        const int i = idx >> 6, l = idx & 63;
        float2 o;
        if (i < 511 && l > (i & 63)) {
            const int col = ((i >> 6) << 6) + l;
            o.x = W_hh[(size_t)i * 512 + col];
            o.y = b_hh[(size_t)i * 512 + col];
        } else { o.x = 0.0f; o.y = -1.0f; }
        wdg[idx] = o;
    } else if (b < 576) {
        const int rb = b - 128;
        if      (rb < 112) pack_bulk<0>(W_hh, b_hh, wbk, (rb      ) * 256 + tid);
        else if (rb < 208) pack_bulk<1>(W_hh, b_hh, wbk, (rb - 112) * 256 + tid);
        else if (rb < 288) pack_bulk<2>(W_hh, b_hh, wbk, (rb - 208) * 256 + tid);
        else if (rb < 352) pack_bulk<3>(W_hh, b_hh, wbk, (rb - 288) * 256 + tid);
        else if (rb < 400) pack_bulk<4>(W_hh, b_hh, wbk, (rb - 352) * 256 + tid);
        else if (rb < 432) pack_bulk<5>(W_hh, b_hh, wbk, (rb - 400) * 256 + tid);
        else               pack_bulk<6>(W_hh, b_hh, wbk, (rb - 432) * 256 + tid);
    } else if (b < 960) {
        convW_body(W_in, Bin, (b - 576) * 256 + tid);
    } else {
        convW_body(W_out, Bout, (b - 960) * 256 + tid);
    }
}

// ---------------------------------------------------------------------------
// MFMA GEMM: 512 threads (8 waves = 2/SIMD). Unchanged (passing r5-r9).
// ---------------------------------------------------------------------------
template <bool ACT>
__global__ __launch_bounds__(512, 2)
void mfma_gemm(const float* __restrict__ A,    // [1024][512] fp32
               const uint4* __restrict__ Bg,   // [48][32][64] uint4
               const float* __restrict__ bias,
               float* __restrict__ C) {
    __shared__ uint4 lds[2][768];
    const int tid  = threadIdx.x;
    const int lane = tid & 63;
    const int w    = tid >> 6;
    const int mfw  = w & 3;
    const int nfw  = w >> 2;
    const int mf0  = blockIdx.x * 4;
    const int nf0  = blockIdx.y * 2;

    const int ks_s = tid >> 8;
    const int mf_s = (tid >> 6) & 3;
    const int arow = (mf0 + mf_s) * 16 + (lane & 15);
    const int koff = (lane >> 4) << 3;
    const int bks  = tid >> 7;
    const int bnf  = (tid >> 6) & 1;

    float4 Ra0, Ra1; uint4 R2;
    auto stage = [&](int s) {
        const int kp = (s * 2 + ks_s) * 32 + koff;
        const int c  = kp & 511;
        Ra0 = *(const float4*)&A[(size_t)arow * 512 + c];
        Ra1 = *(const float4*)&A[(size_t)arow * 512 + c + 4];
        if (tid < 256)
            R2 = Bg[(size_t)((s * 2 + bks) * 32 + nf0 + bnf) * 64 + lane];
    };
    auto write_tile = [&](int buf, int s) {
        const int kp = (s * 2 + ks_s) * 32 + koff;
        lds[buf][ks_s * 256 + mf_s * 64 + lane] = cvt8(Ra0, Ra1, kp >> 9);
        if (tid < 256)
            lds[buf][512 + bks * 128 + bnf * 64 + lane] = R2;
    };

    f32x4 acc = {0.f, 0.f, 0.f, 0.f};

    stage(0);
    write_tile(0, 0);
    stage(1);
    __syncthreads();

    for (int s = 0; s < 24; ++s) {
        const int cur = s & 1;
        if (s + 1 < 24) write_tile(cur ^ 1, s + 1);
        if (s + 2 < 24) stage(s + 2);
        __builtin_amdgcn_sched_barrier(0);

        bf16x8 aF0 = *(const bf16x8*)&lds[cur][          mfw * 64 + lane];
        bf16x8 aF1 = *(const bf16x8*)&lds[cur][256     + mfw * 64 + lane];
        bf16x8 bF0 = *(const bf16x8*)&lds[cur][512     + nfw * 64 + lane];
        bf16x8 bF1 = *(const bf16x8*)&lds[cur][512+128 + nfw * 64 + lane];
        acc = __builtin_amdgcn_mfma_f32_16x16x32_bf16(aF0, bF0, acc, 0, 0, 0);
        acc = __builtin_amdgcn_mfma_f32_16x16x32_bf16(aF1, bF1, acc, 0, 0, 0);
        __syncthreads();
    }

    const int colg  = (nf0 + nfw) * 16 + (lane & 15);
    const float bv  = bias[colg];
    const int rbase = (mf0 + mfw) * 16 + ((lane >> 4) << 2);
    #pragma unroll
    for (int r = 0; r < 4; ++r) {
        float v = acc[r] + bv;
        if (ACT) { v = fmaxf(v, 0.f); v = v * v; }
        C[(size_t)(rbase + r) * 512 + colg] = v;
    }
}

// ---------------------------------------------------------------------------
// Sequential triangular scan, v11: 2 blocks/CU via 512 blocks x 256 threads.
// v8==v9 (60.6us) proved intra-wave-latency-bound at 1 wave/SIMD; v10's
// 512-thread split spilled. v11 keeps the EXACT v8 code shape (256-thread
// block, function-scope arrays, forceinline, gload_lds staging, 2x28KB
// double buffer) and doubles TLP by doubling BLOCKS: block owns 2 rows,
// 4 waves = 2 rows x 2 s-PARITY halves (wave does even or odd steps of
// EVERY tile -> tile flow/staging unchanged, no wave idles). Private
// partial accumulators hrp[8] per wave; at chunk C the odd-parity partial
// for group C is combined via 512B LDS comm before the (even-parity-owned)
// serial diag; final hr[C] broadcast back for the partner's readlanes.
// LDS 57.9KB -> exactly 2 blocks/CU = 2 waves/SIMD.
// FP note: per-group bulk sums now combine even-s/odd-s partials (tiny
// reorder, well under the bf16-split GEMM error); diag order unchanged.
// ---------------------------------------------------------------------------
template <int C>
__device__ __forceinline__ void scan_chunk(const float2* __restrict__ wdg,
                                           const float2* __restrict__ wbk,
                                           float2 (* __restrict__ smb)[3584],
                                           float (* __restrict__ comm)[64],
                                           float hrp[8], int lane, int row_l,
                                           int par, int tid) {
    constexpr int NK = 7 - C;
    constexpr int CB = (C==0?0:C==1?7:C==2?13:C==3?18:C==4?22:C==5?25:C==6?27:27) * 4096;

    const char* gch = (const char*)(wbk + CB);
    char* lbase = (char*)(&smb[0][0]) + ((tid >> 6) << 10);   // + wave*1024
    auto stage = [&](int t, int buf) {
        const char* g = gch + (size_t)t * (NK * 4096);
        char* l = lbase + buf * 28672;
        #pragma unroll
        for (int u = 0; u < NK; ++u)     // dest wave-uniform; HW adds lane*16
            gload_lds16(g + (size_t)((u << 8) + tid) * 16, l + (u << 12));
    };
    // stage tile 0; its flight hides under the handoff + diag below.
    // (buffer 0 was last read 2 barriers ago in the previous chunk -> safe)
    if constexpr (NK > 0) stage(0, 0);
    __builtin_amdgcn_sched_barrier(0);

    // partial handoff: odd wave's accumulated bulk for group C -> even wave
    if (par == 1) comm[row_l][lane] = hrp[C];
    __syncthreads();

    // serial diagonal in the even-parity wave (v8's rotating register window)
    if (par == 0) {
        hrp[C] += comm[row_l][lane];         // combine partials: full hr[C]
        const float2* dptr = wdg + (64 * C) * 64 + lane;
        float2 Wd[16];
        #pragma unroll
        for (int q = 0; q < 16; ++q) Wd[q] = dptr[q * 64];
        for (int t = 0; t < 4; ++t) {
            #pragma unroll
            for (int q = 0; q < 16; ++q) {
                const int s = t * 16 + q;
                if (!(C == 7 && s == 63)) {  // no global step 511
                    const float hi = __uint_as_float(
                        __builtin_amdgcn_readlane(__float_as_uint(hrp[C]), s));
                    const float tv = fmaf(hi, Wd[q].x, Wd[q].y);
                    const float rv = fmaxf(tv, 0.f);
                    hrp[C] = fmaf(rv, rv, hrp[C]);
                }
                if (t < 3) Wd[q] = dptr[(s + 16) * 64];
            }
        }
        comm[row_l][lane] = hrp[C];          // broadcast final for partner
    }
    __syncthreads();                         // final visible; tile 0 resident

    // streaming bulk: hr[C] final -> all readlanes independent.
    // Wave takes s = 8t + 2*sl + par (its parity half of every tile).
    if constexpr (NK > 0) {
        const float hsrc = (par == 0) ? hrp[C] : comm[row_l][lane];
        for (int t = 0; t < 8; ++t) {
            const int buf = t & 1;
            if (t + 1 < 8) stage(t + 1, buf ^ 1);
            __builtin_amdgcn_sched_barrier(0);   // pin issue above compute

            #pragma unroll
            for (int sl = 0; sl < 4; ++sl) {
                const int srow = 2 * sl + par;
                const float hi = __uint_as_float(
                    __builtin_amdgcn_readlane(__float_as_uint(hsrc), t * 8 + srow));
                #pragma unroll
                for (int k = 0; k < NK; ++k) {
                    const float2 wv = smb[buf][(srow * NK + k) * 64 + lane];
                    const float tv = fmaf(hi, wv.x, wv.y);
                    const float rv = fmaxf(tv, 0.f);
                    hrp[C + 1 + k] = fmaf(rv, rv, hrp[C + 1 + k]);
                }
            }
            __syncthreads();                 // reads done; tile t+1 resident
        }
    }
}

__global__ __launch_bounds__(256, 2)
void scan_kernel(const float2* __restrict__ wdg, const float2* __restrict__ wbk,
                 float* __restrict__ h) {
    __shared__ __align__(16) float2 smb[2][3584];   // 2 x 28KB tile buffers
    __shared__ float comm[2][64];                   // per-row handoff, 512B
    const int tid   = threadIdx.x;
    const int lane  = tid & 63;
    const int w     = tid >> 6;
    const int row_l = w & 1;                 // row slot in block
    const int par   = w >> 1;                // s-parity half (0 = diag owner)
    float* hrow = h + (size_t)(blockIdx.x * 2 + row_l) * HH;

    float hrp[8];
    #pragma unroll
    for (int k = 0; k < 8; ++k) hrp[k] = (par == 0) ? hrow[lane + 64 * k] : 0.f;

    scan_chunk<0>(wdg, wbk, smb, comm, hrp, lane, row_l, par, tid);
    scan_chunk<1>(wdg, wbk, smb, comm, hrp, lane, row_l, par, tid);
    scan_chunk<2>(wdg, wbk, smb, comm, hrp, lane, row_l, par, tid);
    scan_chunk<3>(wdg, wbk, smb, comm, hrp, lane, row_l, par, tid);
    scan_chunk<4>(wdg, wbk, smb, comm, hrp, lane, row_l, par, tid);
    scan_chunk<5>(wdg, wbk, smb, comm, hrp, lane, row_l, par, tid);
    scan_chunk<6>(wdg, wbk, smb, comm, hrp, lane, row_l, par, tid);
    scan_chunk<7>(wdg, wbk, smb, comm, hrp, lane, row_l, par, tid);

    // group k finalized at chunk k's diag in the even-parity wave
    if (par == 0) {
        #pragma unroll
        for (int k = 0; k < 8; ++k) hrow[lane + 64 * k] = hrp[k];
    }
}

// ---------------------------------------------------------------------------
// workspace layout (6.2 MB):
//   [0x000000, 0x040000) wdg  (512*64 f2 = 256 KB)
//   [0x040000, 0x120000) wbk  (114688 f2 = 896 KB)
//   [0x120000, 0x320000) h    (1024*512 fp32 = 2 MB)
//   [0x320000, 0x4A0000) Bin  (48*32*64 uint4 = 1.5 MB)
//   [0x4A0000, 0x620000) Bout (1.5 MB)
// ---------------------------------------------------------------------------
extern "C" void kernel_launch(void* const* d_in, const int* in_sizes, int n_in,
                              void* d_out, int out_size, void* d_ws, size_t ws_size,
                              hipStream_t stream) {
    const float* x     = (const float*)d_in[0];
    const float* W_in  = (const float*)d_in[1];
    const float* b_in  = (const float*)d_in[2];
    const float* W_hh  = (const float*)d_in[3];
    const float* b_hh  = (const float*)d_in[4];
    const float* W_out = (const float*)d_in[5];
    const float* b_out = (const float*)d_in[6];
    float* out = (float*)d_out;

    char* ws = (char*)d_ws;
    float2* wdg  = (float2*)ws;
    float2* wbk  = (float2*)(ws + 0x040000u);
    float*  h    = (float*)(ws + 0x120000u);
    uint4*  Bin  = (uint4*)(ws + 0x320000u);
    uint4*  Bout = (uint4*)(ws + 0x4A0000u);

    // 1) prep: scan-weight packs + W_in/W_out bf16 hi/lo frag-linear split
    prep_all<<<dim3(1344), dim3(256), 0, stream>>>(W_hh, b_hh, wdg, wbk,
                                                   W_in, Bin, W_out, Bout);

    // 2) h0 = relu^2(x @ W_in + b_in)  (A-side split fused into staging)
    mfma_gemm<true><<<dim3(16, 16), dim3(512), 0, stream>>>(x, Bin, b_in, h);

    // 3) sequential triangular scan, in-place on h (2 rows/block, s-parity split)
    scan_kernel<<<dim3(512), dim3(256), 0, stream>>>(wdg, wbk, h);

    // 4) out = h @ W_out + b_out  (A-side split fused into staging)
    mfma_gemm<false><<<dim3(16, 16), dim3(512), 0, stream>>>(h, Bout, b_out, out);
}